// Round 13
// baseline (479.395 us; speedup 1.0000x reference)
//
#include <hip/hip_runtime.h>
#include <hip/hip_bf16.h>

#define EMB 1024
#define SEQ 2048
#define BATCH 4
#define TOK (BATCH*SEQ)
#define NH 16
#define DH 64
#define FF 4096

typedef unsigned short u16;
typedef __bf16 bf16x8 __attribute__((ext_vector_type(8)));
typedef float f32x4 __attribute__((ext_vector_type(4)));

union frag_u { uint4 u4; bf16x8 bf; u16 us[8]; };

__device__ __forceinline__ u16 f2bf(float f) {
  union { float f; unsigned u; } a; a.f = f;
  unsigned r = a.u + 0x7fffu + ((a.u >> 16) & 1u);
  return (u16)(r >> 16);
}
__device__ __forceinline__ float bf2f(u16 u) {
  union { unsigned u; float f; } a; a.u = ((unsigned)u) << 16; return a.f;
}
// packed f32 pair -> bf16x2 (RNE), single HW instruction
__device__ __forceinline__ unsigned cvt_pk_bf16(float lo, float hi) {
  unsigned r;
  asm("v_cvt_pk_bf16_f32 %0, %1, %2" : "=v"(r) : "v"(lo), "v"(hi));
  return r;
}
// 2^x via the HW transcendental unit (single v_exp_f32)
__device__ __forceinline__ float exp2_hw(float x) {
  float r;
  asm("v_exp_f32 %0, %1" : "=v"(r) : "v"(x));
  return r;
}

__device__ __forceinline__ void glds16(const void* g, void* l) {
  __builtin_amdgcn_global_load_lds((const __attribute__((address_space(1))) void*)g,
                                   (__attribute__((address_space(3))) void*)l, 16, 0, 0);
}

// fast exact-enough GELU (tanh form, max abs err ~3e-4)
__device__ __forceinline__ float gelu_fast(float u) {
  float u2 = u * u;
  float c = fmaf(u2, 0.0356774081f, 0.7978845608f);
  float e = __expf(2.f * u * c);
  return u * e * __builtin_amdgcn_rcpf(e + 1.f);
}

// ---------------- transpose+convert body: fp32 [K][N] -> bf16 [N][ldk] ----------------
__device__ __forceinline__ void cvt_t_body(const float* __restrict__ src,
                                           u16* __restrict__ dst,
                                           int N, int ldk, int bx, int by) {
  __shared__ float tile[32][33];
  int c0 = bx * 32, r0 = by * 32;
  int tc = threadIdx.x & 31, tr = threadIdx.x >> 5;
  #pragma unroll
  for (int p = 0; p < 4; p++)
    tile[tr + p * 8][tc] = src[(size_t)(r0 + tr + p * 8) * N + c0 + tc];
  __syncthreads();
  #pragma unroll
  for (int p = 0; p < 4; p++)
    dst[(size_t)(c0 + tr + p * 8) * ldk + r0 + tc] = f2bf(tile[tc][tr + p * 8]);
}

// one kernel for all 6 weight transposes (saves 5 launches) — R7 known-good version
__global__ __launch_bounds__(256) void prep_kernel(const float* Wq, const float* Wk,
                                                   const float* Wv, const float* Wo,
                                                   const float* W1, const float* W2,
                                                   u16* wqkv_t, u16* wo_t,
                                                   u16* w1_t, u16* w2_t) {
  int id = blockIdx.x;
  if (id < 4096) {
    const float* s = (id < 1024) ? Wq : (id < 2048) ? Wk : (id < 3072) ? Wv : Wo;
    u16* d = (id < 1024) ? wqkv_t : (id < 2048) ? wqkv_t + 1024 * 1024
           : (id < 3072) ? wqkv_t + 2 * 1024 * 1024 : wo_t;
    int local = id & 1023;
    cvt_t_body(s, d, 1024, 1024, local & 31, local >> 5);
  } else if (id < 8192) {
    int local = id - 4096;
    cvt_t_body(W1, w1_t, 4096, 1024, local & 127, local >> 7);
  } else {
    int local = id - 8192;
    cvt_t_body(W2, w2_t, 1024, 4096, local & 31, local >> 5);
  }
}

// ---------------- LayerNorm, one wave per row; IN_BF16 selects input dtype ----------------
template <int IN_BF16>
__global__ __launch_bounds__(256) void ln_kernel(const void* __restrict__ xv,
                                                 const float* __restrict__ g,
                                                 const float* __restrict__ be,
                                                 u16* __restrict__ out) {
  int wave = threadIdx.x >> 6, lane = threadIdx.x & 63;
  int row = blockIdx.x * 4 + wave;
  float v[16];
  float s = 0.f;
  if (IN_BF16) {
    const u16* xr = (const u16*)xv + (size_t)row * EMB;
    #pragma unroll
    for (int i = 0; i < 4; i++) {
      ushort4 u = *(const ushort4*)(xr + i * 256 + lane * 4);
      v[i * 4 + 0] = bf2f(u.x); v[i * 4 + 1] = bf2f(u.y);
      v[i * 4 + 2] = bf2f(u.z); v[i * 4 + 3] = bf2f(u.w);
      s += v[i * 4] + v[i * 4 + 1] + v[i * 4 + 2] + v[i * 4 + 3];
    }
  } else {
    const float* xr = (const float*)xv + (size_t)row * EMB;
    #pragma unroll
    for (int i = 0; i < 4; i++) {
      float4 u = *(const float4*)(xr + i * 256 + lane * 4);
      v[i * 4 + 0] = u.x; v[i * 4 + 1] = u.y; v[i * 4 + 2] = u.z; v[i * 4 + 3] = u.w;
      s += u.x + u.y + u.z + u.w;
    }
  }
  #pragma unroll
  for (int m = 1; m < 64; m <<= 1) s += __shfl_xor(s, m, 64);
  float mean = s * (1.f / EMB);
  float vs = 0.f;
  #pragma unroll
  for (int i = 0; i < 16; i++) { float dx = v[i] - mean; vs += dx * dx; }
  #pragma unroll
  for (int m = 1; m < 64; m <<= 1) vs += __shfl_xor(vs, m, 64);
  float inv = rsqrtf(vs * (1.f / EMB) + 1e-5f);
  u16* orow = out + (size_t)row * EMB;
  #pragma unroll
  for (int i = 0; i < 4; i++) {
    int c = i * 256 + lane * 4;
    float4 gv = *(const float4*)(g + c);
    float4 bv = *(const float4*)(be + c);
    ushort4 o;
    o.x = f2bf(gv.x * (v[i * 4 + 0] - mean) * inv + bv.x);
    o.y = f2bf(gv.y * (v[i * 4 + 1] - mean) * inv + bv.y);
    o.z = f2bf(gv.z * (v[i * 4 + 2] - mean) * inv + bv.z);
    o.w = f2bf(gv.w * (v[i * 4 + 3] - mean) * inv + bv.w);
    *(ushort4*)(orow + c) = o;
  }
}

// ---------------- 256x128 bf16 MFMA GEMM, BK=64, counted-vmcnt depth-2 pipeline ----------------
// (same recipe as gemm128: 12 VMEM in flight, vmcnt(6) mid-loop, raw barriers, setprio)
// MODE 1: fused-QKV (q scaled by 0.125*log2e; q,k -> [bh][s][d], v -> [bh][d][s])
// MODE 2: +bias GELU bf16 out
template <int MODE>
__global__ __launch_bounds__(512) void gemm256(const u16* __restrict__ A,
                                               const u16* __restrict__ Bt,
                                               const float* __restrict__ bias,
                                               void* __restrict__ outp,
                                               int N, int K) {
  __shared__ __align__(16) u16 As[2][256 * 64];
  __shared__ __align__(16) u16 Bs[2][128 * 64];
  const int t = threadIdx.x;
  const int w = t >> 6, lane = t & 63;
  const int l15 = lane & 15, quad = lane >> 4;
  const int wr = w >> 1, wc = w & 1;

  // XCD-chunked bijective swizzle (nwg % 8 == 0 for all our grids)
  const int gx = gridDim.x;
  const int nwg = gx * gridDim.y;
  const int id0 = blockIdx.y * gx + blockIdx.x;
  const int nid = (id0 & 7) * (nwg >> 3) + (id0 >> 3);
  const int rowBase = (nid / gx) * 256, colBase = (nid % gx) * 128;

  const int sr = lane >> 3;
  const int sc = ((lane & 7) ^ sr) * 8;
  const u16* gA = A + (size_t)(rowBase + w * 8 + sr) * K + sc;
  const u16* gB = Bt + (size_t)(colBase + w * 8 + sr) * K + sc;
  const int ldsA = w * 8 * 64;

  const int swz0 = (quad ^ (l15 & 7)) * 8;
  const int swz1 = ((quad + 4) ^ (l15 & 7)) * 8;

  f32x4 zero = {0.f, 0.f, 0.f, 0.f};
  f32x4 acc[4][4];
  #pragma unroll
  for (int i = 0; i < 4; i++)
    #pragma unroll
    for (int j = 0; j < 4; j++) acc[i][j] = zero;

  const int nt = K >> 6;
  // prologue: tile 0 -> buf0, tile 1 -> buf1 (12 VMEM in flight per thread)
  #pragma unroll
  for (int j = 0; j < 4; j++)
    glds16(gA + (size_t)(j * 64) * K, As[0] + ldsA + j * 64 * 64);
  #pragma unroll
  for (int j = 0; j < 2; j++)
    glds16(gB + (size_t)(j * 64) * K, Bs[0] + ldsA + j * 64 * 64);
  #pragma unroll
  for (int j = 0; j < 4; j++)
    glds16(gA + (size_t)(j * 64) * K + 64, As[1] + ldsA + j * 64 * 64);
  #pragma unroll
  for (int j = 0; j < 2; j++)
    glds16(gB + (size_t)(j * 64) * K + 64, Bs[1] + ldsA + j * 64 * 64);

  for (int tt = 0; tt < nt; tt++) {
    const int cur = tt & 1;
    // wait for this tile's 6 oldest loads; next tile's 6 stay in flight
    if (tt + 1 < nt) asm volatile("s_waitcnt vmcnt(6)" ::: "memory");
    else             asm volatile("s_waitcnt vmcnt(0)" ::: "memory");
    __builtin_amdgcn_sched_barrier(0);
    __builtin_amdgcn_s_barrier();          // raw barrier: no vmcnt(0) drain

    const u16* as = As[cur];
    const u16* bs = Bs[cur];
    #pragma unroll
    for (int kk = 0; kk < 2; kk++) {
      const int so = kk ? swz1 : swz0;
      frag_u a4[4], b4[4];
      #pragma unroll
      for (int mi = 0; mi < 4; mi++)
        a4[mi].u4 = *(const uint4*)(as + (wr * 64 + mi * 16 + l15) * 64 + so);
      #pragma unroll
      for (int ni = 0; ni < 4; ni++)
        b4[ni].u4 = *(const uint4*)(bs + (wc * 64 + ni * 16 + l15) * 64 + so);
      __builtin_amdgcn_s_setprio(1);
      #pragma unroll
      for (int mi = 0; mi < 4; mi++)
        #pragma unroll
        for (int ni = 0; ni < 4; ni++)
          acc[mi][ni] = __builtin_amdgcn_mfma_f32_16x16x32_bf16(a4[mi].bf, b4[ni].bf, acc[mi][ni], 0, 0, 0);
      __builtin_amdgcn_s_setprio(0);
    }
    // all my ds_reads done before anyone overwrites this buffer
    asm volatile("s_waitcnt lgkmcnt(0)" ::: "memory");
    __builtin_amdgcn_sched_barrier(0);
    __builtin_amdgcn_s_barrier();

    if (tt + 2 < nt) {
      const int k0 = (tt + 2) << 6;
      #pragma unroll
      for (int j = 0; j < 4; j++)
        glds16(gA + (size_t)(j * 64) * K + k0, As[cur] + ldsA + j * 64 * 64);
      #pragma unroll
      for (int j = 0; j < 2; j++)
        glds16(gB + (size_t)(j * 64) * K + k0, Bs[cur] + ldsA + j * 64 * 64);
    }
  }

  #pragma unroll
  for (int mi = 0; mi < 4; mi++) {
    #pragma unroll
    for (int ni = 0; ni < 4; ni++) {
      int col = colBase + wc * 64 + ni * 16 + l15;
      int row0 = rowBase + wr * 64 + mi * 16 + quad * 4;
      if (MODE == 1) {
        int mat = col >> 10, cc = col & 1023;
        int hh = cc >> 6, d = cc & 63;
        int b = row0 >> 11, s0 = row0 & 2047;
        if (mat == 2) {
          uint2 pk;
          pk.x = (unsigned)f2bf(acc[mi][ni][0]) | ((unsigned)f2bf(acc[mi][ni][1]) << 16);
          pk.y = (unsigned)f2bf(acc[mi][ni][2]) | ((unsigned)f2bf(acc[mi][ni][3]) << 16);
          *(uint2*)((u16*)outp + 2 * (size_t)TOK * EMB +
                    ((size_t)((b * NH + hh) * DH + d)) * SEQ + s0) = pk;
        } else {
          // q (mat==0) pre-scaled by 0.125*log2(e) so attn can use exp2 directly
          const float m = (mat == 0) ? 0.1803368801f : 1.f;
          #pragma unroll
          for (int r = 0; r < 4; r++)
            ((u16*)outp)[(size_t)mat * (TOK * EMB) +
                         (((size_t)(b * NH + hh) * SEQ + s0 + r) << 6) + d] = f2bf(acc[mi][ni][r] * m);
        }
      } else {
        #pragma unroll
        for (int r = 0; r < 4; r++) {
          float vv = gelu_fast(acc[mi][ni][r] + bias[col]);
          ((u16*)outp)[(size_t)(row0 + r) * N + col] = f2bf(vv);
        }
      }
    }
  }
}

// ---------------- 128x128 GEMM, BK=64, counted-vmcnt deep pipeline (T3/T4) ----------------
// prefetch depth 2 (16 VMEM in flight); raw s_barrier, vmcnt(8) mid-loop (never 0)
// MODE 3: +bias +fp32 resid -> bf16 out; MODE 4: +bias +bf16 resid -> fp32 out
template <int MODE>
__global__ __launch_bounds__(256) void gemm128(const u16* __restrict__ A,
                                               const u16* __restrict__ Bt,
                                               const float* __restrict__ bias,
                                               const void* __restrict__ resid,
                                               void* __restrict__ outp,
                                               int N, int K) {
  __shared__ __align__(16) u16 As[2][128 * 64];
  __shared__ __align__(16) u16 Bs[2][128 * 64];
  const int t = threadIdx.x;
  const int w = t >> 6, lane = t & 63;
  const int l15 = lane & 15, quad = lane >> 4;
  const int wr = w >> 1, wc = w & 1;

  // XCD-chunked bijective swizzle (nwg % 8 == 0 for all our grids)
  const int gx = gridDim.x;
  const int nwg = gx * gridDim.y;
  const int id0 = blockIdx.y * gx + blockIdx.x;
  const int nid = (id0 & 7) * (nwg >> 3) + (id0 >> 3);
  const int rowBase = (nid / gx) * 128, colBase = (nid % gx) * 128;

  const int sr = lane >> 3;
  const int sc = ((lane & 7) ^ sr) * 8;
  const u16* gA = A + (size_t)(rowBase + w * 8 + sr) * K + sc;
  const u16* gB = Bt + (size_t)(colBase + w * 8 + sr) * K + sc;
  const int ldsOff = (w * 8) * 64;

  const int swz0 = (quad ^ (l15 & 7)) * 8;
  const int swz1 = ((quad + 4) ^ (l15 & 7)) * 8;

  f32x4 zero = {0.f, 0.f, 0.f, 0.f};
  f32x4 acc[4][4];
  #pragma unroll
  for (int i = 0; i < 4; i++)
    #pragma unroll
    for (int j = 0; j < 4; j++) acc[i][j] = zero;

  const int nt = K >> 6;
  // prologue: stage tile 0 -> buf0, tile 1 -> buf1 (16 VMEM in flight per wave)
  #pragma unroll
  for (int j = 0; j < 4; j++) {
    glds16(gA + (size_t)(j * 32) * K, As[0] + ldsOff + j * 32 * 64);
    glds16(gB + (size_t)(j * 32) * K, Bs[0] + ldsOff + j * 32 * 64);
  }
  #pragma unroll
  for (int j = 0; j < 4; j++) {
    glds16(gA + (size_t)(j * 32) * K + 64, As[1] + ldsOff + j * 32 * 64);
    glds16(gB + (size_t)(j * 32) * K + 64, Bs[1] + ldsOff + j * 32 * 64);
  }

  for (int tt = 0; tt < nt; tt++) {
    const int cur = tt & 1;
    // wait only for the OLDEST 8 loads (this tile); next tile's 8 stay in flight
    if (tt + 1 < nt) asm volatile("s_waitcnt vmcnt(8)" ::: "memory");
    else             asm volatile("s_waitcnt vmcnt(0)" ::: "memory");
    __builtin_amdgcn_sched_barrier(0);
    __builtin_amdgcn_s_barrier();          // raw barrier: no implicit vmcnt(0) drain

    const u16* as = As[cur];
    const u16* bs = Bs[cur];
    #pragma unroll
    for (int kk = 0; kk < 2; kk++) {
      const int so = kk ? swz1 : swz0;
      frag_u a4[4], b4[4];
      #pragma unroll
      for (int mi = 0; mi < 4; mi++)
        a4[mi].u4 = *(const uint4*)(as + (wr * 64 + mi * 16 + l15) * 64 + so);
      #pragma unroll
      for (int ni = 0; ni < 4; ni++)
        b4[ni].u4 = *(const uint4*)(bs + (wc * 64 + ni * 16 + l15) * 64 + so);
      __builtin_amdgcn_s_setprio(1);
      #pragma unroll
      for (int mi = 0; mi < 4; mi++)
        #pragma unroll
        for (int ni = 0; ni < 4; ni++)
          acc[mi][ni] = __builtin_amdgcn_mfma_f32_16x16x32_bf16(a4[mi].bf, b4[ni].bf, acc[mi][ni], 0, 0, 0);
      __builtin_amdgcn_s_setprio(0);
    }
    // all my ds_reads complete before anyone overwrites this buffer
    asm volatile("s_waitcnt lgkmcnt(0)" ::: "memory");
    __builtin_amdgcn_sched_barrier(0);
    __builtin_amdgcn_s_barrier();

    if (tt + 2 < nt) {
      const int k0 = (tt + 2) << 6;
      #pragma unroll
      for (int j = 0; j < 4; j++) {
        glds16(gA + (size_t)(j * 32) * K + k0, As[cur] + ldsOff + j * 32 * 64);
        glds16(gB + (size_t)(j * 32) * K + k0, Bs[cur] + ldsOff + j * 32 * 64);
      }
    }
  }

  #pragma unroll
  for (int mi = 0; mi < 4; mi++) {
    #pragma unroll
    for (int ni = 0; ni < 4; ni++) {
      int col = colBase + wc * 64 + ni * 16 + l15;
      int row0 = rowBase + wr * 64 + mi * 16 + quad * 4;
      #pragma unroll
      for (int r = 0; r < 4; r++) {
        int row = row0 + r;
        float vv = acc[mi][ni][r] + bias[col];
        if (MODE == 3) {
          vv += ((const float*)resid)[(size_t)row * N + col];
          ((u16*)outp)[(size_t)row * N + col] = f2bf(vv);
        } else {
          vv += bf2f(((const u16*)resid)[(size_t)row * N + col]);
          ((float*)outp)[(size_t)row * N + col] = vv;
        }
      }
    }
  }
}

// ---------------- flash attention v6: static heavy-first, exp2 + cvt_pk softmax ----------------
// grid (64 bh, 16 qt); q pre-scaled by 0.125*log2e so P = exp2(S)  [R10 known-good]
__global__ __launch_bounds__(256) void attn_kernel(const u16* __restrict__ q,
                                                   const u16* __restrict__ k,
                                                   const u16* __restrict__ vt,
                                                   u16* __restrict__ ctx) {
  __shared__ __align__(16) u16 Ks[64 * 64];   // [kpos][d], XOR-swizzled
  __shared__ __align__(16) u16 Vs[64 * 64];   // [d][kpos], XOR-swizzled
  __shared__ __align__(16) u16 Ps[128 * 64];  // [qrow][kpos], XOR-swizzled
  __shared__ float Ls[128];
  const int t = threadIdx.x;
  const int w = t >> 6, lane = t & 63;
  const int l15 = lane & 15, quad = lane >> 4;
  const int bh = blockIdx.x;
  const int qt = 15 - (int)blockIdx.y;   // heaviest blocks dispatched first
  const size_t base = (size_t)bh * SEQ * DH;
  const int bq = bh >> 4, hh = bh & 15;
  const int qBase = qt * 128;
  const int ktEnd = 2 * qt + 1;
  const int l7 = l15 & 7;

  // staging: each thread owns rows r0 and r0+8 at column-group scg (8 u16 = 16 B)
  const int r0 = w * 16 + (lane >> 3);
  const int scg = lane & 7;
  const int swzs = (scg ^ (r0 & 7)) * 8;       // (r0+8)&7 == r0&7
  const u16* gK = k + base + (size_t)r0 * DH + scg * 8;
  const u16* gV = vt + base + (size_t)r0 * SEQ + scg * 8;
  u16* sK0 = Ks + r0 * 64 + swzs;
  u16* sK1 = Ks + (r0 + 8) * 64 + swzs;
  u16* sV0 = Vs + r0 * 64 + swzs;
  u16* sV1 = Vs + (r0 + 8) * 64 + swzs;

  // Q fragments held in registers for the whole block
  frag_u qf[2][2];
  #pragma unroll
  for (int ni = 0; ni < 2; ni++)
    #pragma unroll
    for (int ks = 0; ks < 2; ks++)
      qf[ni][ks].u4 = *(const uint4*)(q + base +
          (size_t)(qBase + w * 32 + ni * 16 + l15) * DH + ks * 32 + quad * 8);

  f32x4 zero = {0.f, 0.f, 0.f, 0.f};
  f32x4 oacc[2][4];
  #pragma unroll
  for (int mi = 0; mi < 2; mi++)
    #pragma unroll
    for (int n0 = 0; n0 < 4; n0++) oacc[mi][n0] = zero;
  float l0 = 0.f, l1 = 0.f;

  uint4 rK0 = *(const uint4*)(gK);
  uint4 rK1 = *(const uint4*)(gK + 8 * DH);
  uint4 rV0 = *(const uint4*)(gV);
  uint4 rV1 = *(const uint4*)(gV + (size_t)8 * SEQ);

  for (int kt = 0; kt <= ktEnd; kt++) {
    __syncthreads();
    *(uint4*)sK0 = rK0; *(uint4*)sK1 = rK1;
    *(uint4*)sV0 = rV0; *(uint4*)sV1 = rV1;
    __syncthreads();
    if (kt < ktEnd) {
      const int no = (kt + 1) * 64;
      rK0 = *(const uint4*)(gK + (size_t)no * DH);
      rK1 = *(const uint4*)(gK + (size_t)(no + 8) * DH);
      rV0 = *(const uint4*)(gV + no);
      rV1 = *(const uint4*)(gV + (size_t)8 * SEQ + no);
    }
    const int rel = kt - 2 * qt;
    if (rel == 1 && w < 2) continue;   // fully-masked half-tile

    // K fragments (swizzled read, conflict-free)
    frag_u kf[4][2];
    #pragma unroll
    for (int mi = 0; mi < 4; mi++)
      #pragma unroll
      for (int ks = 0; ks < 2; ks++)
        kf[mi][ks].u4 = *(const uint4*)(Ks + (mi * 16 + l15) * 64 + (((ks * 4 + quad) ^ l7) * 8));
    f32x4 st[4][2];
    #pragma unroll
    for (int mi = 0; mi < 4; mi++)
      #pragma unroll
      for (int ni = 0; ni < 2; ni++) st[mi][ni] = zero;
    __builtin_amdgcn_s_setprio(1);
    #pragma unroll
    for (int ks = 0; ks < 2; ks++)
      #pragma unroll
      for (int mi = 0; mi < 4; mi++)
        #pragma unroll
        for (int ni = 0; ni < 2; ni++)
          st[mi][ni] = __builtin_amdgcn_mfma_f32_16x16x32_bf16(kf[mi][ks].bf, qf[ni][ks].bf, st[mi][ni], 0, 0, 0);
    __builtin_amdgcn_s_setprio(0);

    const bool doMask = (rel == 0 && w < 2) || (rel == 1);
    #pragma unroll
    for (int ni = 0; ni < 2; ni++) {
      const int qrow = qBase + w * 32 + ni * 16 + l15;
      float sum = 0.f;
      u16* prow = Ps + (w * 32 + ni * 16 + l15) * 64;   // row&7 == l7
      #pragma unroll
      for (int mi = 0; mi < 4; mi++) {
        float p[4];
        if (doMask) {
          #pragma unroll
          for (int r = 0; r < 4; r++) {
            p[r] = exp2_hw(st[mi][ni][r]);
            if ((kt * 64 + mi * 16 + quad * 4 + r) > qrow) p[r] = 0.f;
            sum += p[r];
          }
        } else {
          #pragma unroll
          for (int r = 0; r < 4; r++) {
            p[r] = exp2_hw(st[mi][ni][r]);
            sum += p[r];
          }
        }
        uint2 pk;
        pk.x = cvt_pk_bf16(p[0], p[1]);
        pk.y = cvt_pk_bf16(p[2], p[3]);
        // col = mi*16 + quad*4 -> group mi*2+(quad>>1), sub-offset (quad&1)*4
        *(uint2*)(prow + (((mi * 2 + (quad >> 1)) ^ l7) * 8) + (quad & 1) * 4) = pk;
      }
      sum += __shfl_xor(sum, 16, 64);
      sum += __shfl_xor(sum, 32, 64);
      if (ni == 0) l0 += sum; else l1 += sum;
    }

    frag_u pa[2][2];
    #pragma unroll
    for (int mi = 0; mi < 2; mi++)
      #pragma unroll
      for (int ks = 0; ks < 2; ks++)
        pa[mi][ks].u4 = *(const uint4*)(Ps + (w * 32 + mi * 16 + l15) * 64 + (((ks * 4 + quad) ^ l7) * 8));
    __builtin_amdgcn_s_setprio(1);
    #pragma unroll
    for (int ks = 0; ks < 2; ks++)
      #pragma unroll
      for (int n0 = 0; n0 < 4; n0++) {
        frag_u b;
        b.u4 = *(const uint4*)(Vs + (n0 * 16 + l15) * 64 + (((ks * 4 + quad) ^ l7) * 8));
        #pragma unroll
        for (int mi = 0; mi < 2; mi++)
          oacc[mi][n0] = __builtin_amdgcn_mfma_f32_16x16x32_bf16(pa[mi][ks].bf, b.bf, oacc[mi][n0], 0, 0, 0);
      }
    __builtin_amdgcn_s_setprio(0);
  }

  if (quad == 0) {
    Ls[w * 32 + l15] = l0;
    Ls[w * 32 + 16 + l15] = l1;
  }
  #pragma unroll
  for (int mi = 0; mi < 2; mi++) {
    float il[4];
    #pragma unroll
    for (int r = 0; r < 4; r++) il[r] = 1.f / Ls[w * 32 + mi * 16 + quad * 4 + r];
    #pragma unroll
    for (int n0 = 0; n0 < 4; n0++) {
      int s = qBase + w * 32 + mi * 16 + quad * 4;
      int col = hh * 64 + n0 * 16 + l15;
      #pragma unroll
      for (int r = 0; r < 4; r++)
        ctx[((size_t)(bq * SEQ + s + r)) * EMB + col] = f2bf(oacc[mi][n0][r] * il[r]);
    }
  }
}

extern "C" void kernel_launch(void* const* d_in, const int* in_sizes, int n_in,
                              void* d_out, int out_size, void* d_ws, size_t ws_size,
                              hipStream_t stream) {
  const float* x  = (const float*)d_in[0];
  const float* Wq = (const float*)d_in[1];
  const float* Wk = (const float*)d_in[2];
  const float* Wv = (const float*)d_in[3];
  const float* Wo = (const float*)d_in[4];
  const float* bo = (const float*)d_in[5];
  const float* W1 = (const float*)d_in[6];
  const float* b1 = (const float*)d_in[7];
  const float* W2 = (const float*)d_in[8];
  const float* b2 = (const float*)d_in[9];
  const float* g1  = (const float*)d_in[10];
  const float* be1 = (const float*)d_in[11];
  const float* g2  = (const float*)d_in[12];
  const float* be2 = (const float*)d_in[13];
  float* out = (float*)d_out;
  char* ws = (char*)d_ws;
  const size_t MB = 1u << 20;

  u16* wqkv_t = (u16*)(ws + 0 * MB);          // 6 MB
  u16* wo_t   = (u16*)(ws + 6 * MB);          // 2 MB
  u16* w1_t   = (u16*)(ws + 8 * MB);          // 8 MB
  u16* w2_t   = (u16*)(ws + 16 * MB);         // 8 MB
  u16* hbuf   = (u16*)(ws + 24 * MB);         // 16 MB bf16 residual h
  u16* r1 = (u16*)(ws + 56 * MB);             // 16 MB: xn1 -> ctx -> xn2
  u16* qb = (u16*)(ws + 72 * MB);             // q,k 16 MB each; vt 16 MB [bh][d][s]
  u16* f1 = (u16*)(ws + 72 * MB);             // 64 MB, overlaps q/k/vt (dead after attn)

  // 1. all weights -> bf16 transposed (one dispatch) — R7 known-good prep
  prep_kernel<<<12288, 256, 0, stream>>>(Wq, Wk, Wv, Wo, W1, W2,
                                         wqkv_t, wo_t, w1_t, w2_t);

  // 2. LN1(x) -> xn1
  ln_kernel<0><<<2048, 256, 0, stream>>>(x, g1, be1, r1);

  // 3. fused QKV (256x128 tiles); q,k row-major, v transposed to [bh][d][s]
  gemm256<1><<<dim3(24, 32), 512, 0, stream>>>(r1, wqkv_t, nullptr, qb, 3072, 1024);

  // 4. causal attention -> ctx  (one q-tile per block, heavy-first)
  attn_kernel<<<dim3(64, 16), 256, 0, stream>>>(qb, qb + (size_t)TOK * EMB,
                                                qb + 2 * (size_t)TOK * EMB, r1);

  // 5. Wo + bo + x -> h (bf16)
  gemm128<3><<<dim3(8, 64), 256, 0, stream>>>(r1, wo_t, bo, x, hbuf, 1024, 1024);

  // 6. LN2(h) -> xn2
  ln_kernel<1><<<2048, 256, 0, stream>>>(hbuf, g2, be2, r1);

  // 7. FFN1: GELU(xn2 @ W1 + b1) -> f1 (256x128 tiles)
  gemm256<2><<<dim3(32, 32), 512, 0, stream>>>(r1, w1_t, b1, f1, 4096, 1024);

  // 8. FFN2: f1 @ W2 + b2 + h -> out (fp32)
  gemm128<4><<<dim3(8, 64), 256, 0, stream>>>(f1, w2_t, b2, hbuf, out, 1024, 4096);
}

// Round 14
// 434.746 us; speedup vs baseline: 1.1027x; 1.1027x over previous
//
#include <hip/hip_runtime.h>
#include <hip/hip_bf16.h>

#define EMB 1024
#define SEQ 2048
#define BATCH 4
#define TOK (BATCH*SEQ)
#define NH 16
#define DH 64
#define FF 4096

typedef unsigned short u16;
typedef __bf16 bf16x8 __attribute__((ext_vector_type(8)));
typedef float f32x4 __attribute__((ext_vector_type(4)));

union frag_u { uint4 u4; bf16x8 bf; u16 us[8]; };

__device__ __forceinline__ u16 f2bf(float f) {
  union { float f; unsigned u; } a; a.f = f;
  unsigned r = a.u + 0x7fffu + ((a.u >> 16) & 1u);
  return (u16)(r >> 16);
}
__device__ __forceinline__ float bf2f(u16 u) {
  union { unsigned u; float f; } a; a.u = ((unsigned)u) << 16; return a.f;
}
// packed f32 pair -> bf16x2 (RNE), single HW instruction
__device__ __forceinline__ unsigned cvt_pk_bf16(float lo, float hi) {
  unsigned r;
  asm("v_cvt_pk_bf16_f32 %0, %1, %2" : "=v"(r) : "v"(lo), "v"(hi));
  return r;
}
// 2^x via the HW transcendental unit (single v_exp_f32)
__device__ __forceinline__ float exp2_hw(float x) {
  float r;
  asm("v_exp_f32 %0, %1" : "=v"(r) : "v"(x));
  return r;
}

__device__ __forceinline__ void glds16(const void* g, void* l) {
  __builtin_amdgcn_global_load_lds((const __attribute__((address_space(1))) void*)g,
                                   (__attribute__((address_space(3))) void*)l, 16, 0, 0);
}

// fast exact-enough GELU (tanh form, max abs err ~3e-4)
__device__ __forceinline__ float gelu_fast(float u) {
  float u2 = u * u;
  float c = fmaf(u2, 0.0356774081f, 0.7978845608f);
  float e = __expf(2.f * u * c);
  return u * e * __builtin_amdgcn_rcpf(e + 1.f);
}

// ---------------- transpose+convert body: fp32 [K][N] -> bf16 [N][ldk] ----------------
__device__ __forceinline__ void cvt_t_body(const float* __restrict__ src,
                                           u16* __restrict__ dst,
                                           int N, int ldk, int bx, int by) {
  __shared__ float tile[32][33];
  int c0 = bx * 32, r0 = by * 32;
  int tc = threadIdx.x & 31, tr = threadIdx.x >> 5;
  #pragma unroll
  for (int p = 0; p < 4; p++)
    tile[tr + p * 8][tc] = src[(size_t)(r0 + tr + p * 8) * N + c0 + tc];
  __syncthreads();
  #pragma unroll
  for (int p = 0; p < 4; p++)
    dst[(size_t)(c0 + tr + p * 8) * ldk + r0 + tc] = f2bf(tile[tc][tr + p * 8]);
}

// ---------------- LayerNorm body, one wave per row; IN_BF16 selects input dtype ----------------
template <int IN_BF16>
__device__ __forceinline__ void ln_body(const void* __restrict__ xv,
                                        const float* __restrict__ g,
                                        const float* __restrict__ be,
                                        u16* __restrict__ out, int blk) {
  int wave = threadIdx.x >> 6, lane = threadIdx.x & 63;
  int row = blk * 4 + wave;
  float v[16];
  float s = 0.f;
  if (IN_BF16) {
    const u16* xr = (const u16*)xv + (size_t)row * EMB;
    #pragma unroll
    for (int i = 0; i < 4; i++) {
      ushort4 u = *(const ushort4*)(xr + i * 256 + lane * 4);
      v[i * 4 + 0] = bf2f(u.x); v[i * 4 + 1] = bf2f(u.y);
      v[i * 4 + 2] = bf2f(u.z); v[i * 4 + 3] = bf2f(u.w);
      s += v[i * 4] + v[i * 4 + 1] + v[i * 4 + 2] + v[i * 4 + 3];
    }
  } else {
    const float* xr = (const float*)xv + (size_t)row * EMB;
    #pragma unroll
    for (int i = 0; i < 4; i++) {
      float4 u = *(const float4*)(xr + i * 256 + lane * 4);
      v[i * 4 + 0] = u.x; v[i * 4 + 1] = u.y; v[i * 4 + 2] = u.z; v[i * 4 + 3] = u.w;
      s += u.x + u.y + u.z + u.w;
    }
  }
  #pragma unroll
  for (int m = 1; m < 64; m <<= 1) s += __shfl_xor(s, m, 64);
  float mean = s * (1.f / EMB);
  float vs = 0.f;
  #pragma unroll
  for (int i = 0; i < 16; i++) { float dx = v[i] - mean; vs += dx * dx; }
  #pragma unroll
  for (int m = 1; m < 64; m <<= 1) vs += __shfl_xor(vs, m, 64);
  float inv = rsqrtf(vs * (1.f / EMB) + 1e-5f);
  u16* orow = out + (size_t)row * EMB;
  #pragma unroll
  for (int i = 0; i < 4; i++) {
    int c = i * 256 + lane * 4;
    float4 gv = *(const float4*)(g + c);
    float4 bv = *(const float4*)(be + c);
    ushort4 o;
    o.x = f2bf(gv.x * (v[i * 4 + 0] - mean) * inv + bv.x);
    o.y = f2bf(gv.y * (v[i * 4 + 1] - mean) * inv + bv.y);
    o.z = f2bf(gv.z * (v[i * 4 + 2] - mean) * inv + bv.z);
    o.w = f2bf(gv.w * (v[i * 4 + 3] - mean) * inv + bv.w);
    *(ushort4*)(orow + c) = o;
  }
}

template <int IN_BF16>
__global__ __launch_bounds__(256) void ln_kernel(const void* __restrict__ xv,
                                                 const float* __restrict__ g,
                                                 const float* __restrict__ be,
                                                 u16* __restrict__ out) {
  ln_body<IN_BF16>(xv, g, be, out, blockIdx.x);
}

// ---- prep: 6 weight transposes (R7 32x32 bodies, same block mapping) + LN1 fold ----
// blocks [0,12288): transposes exactly as R7; [12288,14336): LN1 rows
__global__ __launch_bounds__(256) void prep_kernel(const float* Wq, const float* Wk,
                                                   const float* Wv, const float* Wo,
                                                   const float* W1, const float* W2,
                                                   u16* wqkv_t, u16* wo_t,
                                                   u16* w1_t, u16* w2_t,
                                                   const float* x, const float* g1,
                                                   const float* be1, u16* xn1) {
  int id = blockIdx.x;
  if (id < 4096) {
    const float* s = (id < 1024) ? Wq : (id < 2048) ? Wk : (id < 3072) ? Wv : Wo;
    u16* d = (id < 1024) ? wqkv_t : (id < 2048) ? wqkv_t + 1024 * 1024
           : (id < 3072) ? wqkv_t + 2 * 1024 * 1024 : wo_t;
    int local = id & 1023;
    cvt_t_body(s, d, 1024, 1024, local & 31, local >> 5);
  } else if (id < 8192) {
    int local = id - 4096;
    cvt_t_body(W1, w1_t, 4096, 1024, local & 127, local >> 7);
  } else if (id < 12288) {
    int local = id - 8192;
    cvt_t_body(W2, w2_t, 1024, 4096, local & 31, local >> 5);
  } else {
    ln_body<0>(x, g1, be1, xn1, id - 12288);
  }
}

// ---------------- 256x128 bf16 MFMA GEMM, BK=64, XOR swizzle, 512 thr (R10 known-good) ----------------
// MODE 1: fused-QKV (q scaled by 0.125*log2e; q,k -> [bh][s][d], v -> [bh][d][s])
// MODE 2: +bias GELU bf16 out
template <int MODE>
__global__ __launch_bounds__(512) void gemm256(const u16* __restrict__ A,
                                               const u16* __restrict__ Bt,
                                               const float* __restrict__ bias,
                                               void* __restrict__ outp,
                                               int N, int K) {
  __shared__ __align__(16) u16 As[256 * 64];
  __shared__ __align__(16) u16 Bs[128 * 64];
  const int t = threadIdx.x;
  const int w = t >> 6, lane = t & 63;
  const int l15 = lane & 15, quad = lane >> 4;
  const int wr = w >> 1, wc = w & 1;

  // XCD-chunked bijective swizzle (nwg % 8 == 0 for all our grids)
  const int gx = gridDim.x;
  const int nwg = gx * gridDim.y;
  const int id0 = blockIdx.y * gx + blockIdx.x;
  const int nid = (id0 & 7) * (nwg >> 3) + (id0 >> 3);
  const int rowBase = (nid / gx) * 256, colBase = (nid % gx) * 128;

  const int sr = lane >> 3;
  const int sc = ((lane & 7) ^ sr) * 8;
  const u16* gA = A + (size_t)(rowBase + w * 8 + sr) * K + sc;
  const u16* gB = Bt + (size_t)(colBase + w * 8 + sr) * K + sc;
  u16* lA = As + w * 8 * 64;
  u16* lB = Bs + w * 8 * 64;

  const int swz0 = (quad ^ (l15 & 7)) * 8;
  const int swz1 = ((quad + 4) ^ (l15 & 7)) * 8;

  f32x4 zero = {0.f, 0.f, 0.f, 0.f};
  f32x4 acc[4][4];
  #pragma unroll
  for (int i = 0; i < 4; i++)
    #pragma unroll
    for (int j = 0; j < 4; j++) acc[i][j] = zero;

  for (int k0 = 0; k0 < K; k0 += 64) {
    __syncthreads();
    #pragma unroll
    for (int j = 0; j < 4; j++)
      glds16(gA + (size_t)(j * 64) * K + k0, lA + j * 64 * 64);
    #pragma unroll
    for (int j = 0; j < 2; j++)
      glds16(gB + (size_t)(j * 64) * K + k0, lB + j * 64 * 64);
    __syncthreads();
    #pragma unroll
    for (int kk = 0; kk < 2; kk++) {
      const int so = kk ? swz1 : swz0;
      frag_u a4[4], b4[4];
      #pragma unroll
      for (int mi = 0; mi < 4; mi++)
        a4[mi].u4 = *(const uint4*)(As + (wr * 64 + mi * 16 + l15) * 64 + so);
      #pragma unroll
      for (int ni = 0; ni < 4; ni++)
        b4[ni].u4 = *(const uint4*)(Bs + (wc * 64 + ni * 16 + l15) * 64 + so);
      #pragma unroll
      for (int mi = 0; mi < 4; mi++)
        #pragma unroll
        for (int ni = 0; ni < 4; ni++)
          acc[mi][ni] = __builtin_amdgcn_mfma_f32_16x16x32_bf16(a4[mi].bf, b4[ni].bf, acc[mi][ni], 0, 0, 0);
    }
  }

  #pragma unroll
  for (int mi = 0; mi < 4; mi++) {
    #pragma unroll
    for (int ni = 0; ni < 4; ni++) {
      int col = colBase + wc * 64 + ni * 16 + l15;
      int row0 = rowBase + wr * 64 + mi * 16 + quad * 4;
      if (MODE == 1) {
        int mat = col >> 10, cc = col & 1023;
        int hh = cc >> 6, d = cc & 63;
        int b = row0 >> 11, s0 = row0 & 2047;
        if (mat == 2) {
          uint2 pk;
          pk.x = (unsigned)f2bf(acc[mi][ni][0]) | ((unsigned)f2bf(acc[mi][ni][1]) << 16);
          pk.y = (unsigned)f2bf(acc[mi][ni][2]) | ((unsigned)f2bf(acc[mi][ni][3]) << 16);
          *(uint2*)((u16*)outp + 2 * (size_t)TOK * EMB +
                    ((size_t)((b * NH + hh) * DH + d)) * SEQ + s0) = pk;
        } else {
          // q (mat==0) pre-scaled by 0.125*log2(e) so attn can use exp2 directly
          const float m = (mat == 0) ? 0.1803368801f : 1.f;
          #pragma unroll
          for (int r = 0; r < 4; r++)
            ((u16*)outp)[(size_t)mat * (TOK * EMB) +
                         (((size_t)(b * NH + hh) * SEQ + s0 + r) << 6) + d] = f2bf(acc[mi][ni][r] * m);
        }
      } else {
        #pragma unroll
        for (int r = 0; r < 4; r++) {
          float vv = gelu_fast(acc[mi][ni][r] + bias[col]);
          ((u16*)outp)[(size_t)(row0 + r) * N + col] = f2bf(vv);
        }
      }
    }
  }
}

// ---------------- 128x128 GEMM, BK=64, counted-vmcnt deep pipeline (T3/T4) ----------------
// prefetch depth 2 (16 VMEM in flight); raw s_barrier, vmcnt(8) mid-loop (never 0)
// MODE 3: +bias +fp32 resid -> bf16 out; MODE 4: +bias +bf16 resid -> fp32 out
template <int MODE>
__global__ __launch_bounds__(256) void gemm128(const u16* __restrict__ A,
                                               const u16* __restrict__ Bt,
                                               const float* __restrict__ bias,
                                               const void* __restrict__ resid,
                                               void* __restrict__ outp,
                                               int N, int K) {
  __shared__ __align__(16) u16 As[2][128 * 64];
  __shared__ __align__(16) u16 Bs[2][128 * 64];
  const int t = threadIdx.x;
  const int w = t >> 6, lane = t & 63;
  const int l15 = lane & 15, quad = lane >> 4;
  const int wr = w >> 1, wc = w & 1;

  // XCD-chunked bijective swizzle (nwg % 8 == 0 for all our grids)
  const int gx = gridDim.x;
  const int nwg = gx * gridDim.y;
  const int id0 = blockIdx.y * gx + blockIdx.x;
  const int nid = (id0 & 7) * (nwg >> 3) + (id0 >> 3);
  const int rowBase = (nid / gx) * 128, colBase = (nid % gx) * 128;

  const int sr = lane >> 3;
  const int sc = ((lane & 7) ^ sr) * 8;
  const u16* gA = A + (size_t)(rowBase + w * 8 + sr) * K + sc;
  const u16* gB = Bt + (size_t)(colBase + w * 8 + sr) * K + sc;
  const int ldsOff = (w * 8) * 64;

  const int swz0 = (quad ^ (l15 & 7)) * 8;
  const int swz1 = ((quad + 4) ^ (l15 & 7)) * 8;

  f32x4 zero = {0.f, 0.f, 0.f, 0.f};
  f32x4 acc[4][4];
  #pragma unroll
  for (int i = 0; i < 4; i++)
    #pragma unroll
    for (int j = 0; j < 4; j++) acc[i][j] = zero;

  const int nt = K >> 6;
  // prologue: stage tile 0 -> buf0, tile 1 -> buf1 (16 VMEM in flight per wave)
  #pragma unroll
  for (int j = 0; j < 4; j++) {
    glds16(gA + (size_t)(j * 32) * K, As[0] + ldsOff + j * 32 * 64);
    glds16(gB + (size_t)(j * 32) * K, Bs[0] + ldsOff + j * 32 * 64);
  }
  #pragma unroll
  for (int j = 0; j < 4; j++) {
    glds16(gA + (size_t)(j * 32) * K + 64, As[1] + ldsOff + j * 32 * 64);
    glds16(gB + (size_t)(j * 32) * K + 64, Bs[1] + ldsOff + j * 32 * 64);
  }

  for (int tt = 0; tt < nt; tt++) {
    const int cur = tt & 1;
    // wait only for the OLDEST 8 loads (this tile); next tile's 8 stay in flight
    if (tt + 1 < nt) asm volatile("s_waitcnt vmcnt(8)" ::: "memory");
    else             asm volatile("s_waitcnt vmcnt(0)" ::: "memory");
    __builtin_amdgcn_sched_barrier(0);
    __builtin_amdgcn_s_barrier();          // raw barrier: no implicit vmcnt(0) drain

    const u16* as = As[cur];
    const u16* bs = Bs[cur];
    #pragma unroll
    for (int kk = 0; kk < 2; kk++) {
      const int so = kk ? swz1 : swz0;
      frag_u a4[4], b4[4];
      #pragma unroll
      for (int mi = 0; mi < 4; mi++)
        a4[mi].u4 = *(const uint4*)(as + (wr * 64 + mi * 16 + l15) * 64 + so);
      #pragma unroll
      for (int ni = 0; ni < 4; ni++)
        b4[ni].u4 = *(const uint4*)(bs + (wc * 64 + ni * 16 + l15) * 64 + so);
      __builtin_amdgcn_s_setprio(1);
      #pragma unroll
      for (int mi = 0; mi < 4; mi++)
        #pragma unroll
        for (int ni = 0; ni < 4; ni++)
          acc[mi][ni] = __builtin_amdgcn_mfma_f32_16x16x32_bf16(a4[mi].bf, b4[ni].bf, acc[mi][ni], 0, 0, 0);
      __builtin_amdgcn_s_setprio(0);
    }
    // all my ds_reads complete before anyone overwrites this buffer
    asm volatile("s_waitcnt lgkmcnt(0)" ::: "memory");
    __builtin_amdgcn_sched_barrier(0);
    __builtin_amdgcn_s_barrier();

    if (tt + 2 < nt) {
      const int k0 = (tt + 2) << 6;
      #pragma unroll
      for (int j = 0; j < 4; j++) {
        glds16(gA + (size_t)(j * 32) * K + k0, As[cur] + ldsOff + j * 32 * 64);
        glds16(gB + (size_t)(j * 32) * K + k0, Bs[cur] + ldsOff + j * 32 * 64);
      }
    }
  }

  #pragma unroll
  for (int mi = 0; mi < 4; mi++) {
    #pragma unroll
    for (int ni = 0; ni < 4; ni++) {
      int col = colBase + wc * 64 + ni * 16 + l15;
      int row0 = rowBase + wr * 64 + mi * 16 + quad * 4;
      #pragma unroll
      for (int r = 0; r < 4; r++) {
        int row = row0 + r;
        float vv = acc[mi][ni][r] + bias[col];
        if (MODE == 3) {
          vv += ((const float*)resid)[(size_t)row * N + col];
          ((u16*)outp)[(size_t)row * N + col] = f2bf(vv);
        } else {
          vv += bf2f(((const u16*)resid)[(size_t)row * N + col]);
          ((float*)outp)[(size_t)row * N + col] = vv;
        }
      }
    }
  }
}

// ---------------- flash attention v6: static heavy-first, exp2 + cvt_pk softmax ----------------
// grid (64 bh, 16 qt); q pre-scaled by 0.125*log2e so P = exp2(S)  [R10 known-good]
__global__ __launch_bounds__(256) void attn_kernel(const u16* __restrict__ q,
                                                   const u16* __restrict__ k,
                                                   const u16* __restrict__ vt,
                                                   u16* __restrict__ ctx) {
  __shared__ __align__(16) u16 Ks[64 * 64];   // [kpos][d], XOR-swizzled
  __shared__ __align__(16) u16 Vs[64 * 64];   // [d][kpos], XOR-swizzled
  __shared__ __align__(16) u16 Ps[128 * 64];  // [qrow][kpos], XOR-swizzled
  __shared__ float Ls[128];
  const int t = threadIdx.x;
  const int w = t >> 6, lane = t & 63;
  const int l15 = lane & 15, quad = lane >> 4;
  const int bh = blockIdx.x;
  const int qt = 15 - (int)blockIdx.y;   // heaviest blocks dispatched first
  const size_t base = (size_t)bh * SEQ * DH;
  const int bq = bh >> 4, hh = bh & 15;
  const int qBase = qt * 128;
  const int ktEnd = 2 * qt + 1;
  const int l7 = l15 & 7;

  // staging: each thread owns rows r0 and r0+8 at column-group scg (8 u16 = 16 B)
  const int r0 = w * 16 + (lane >> 3);
  const int scg = lane & 7;
  const int swzs = (scg ^ (r0 & 7)) * 8;       // (r0+8)&7 == r0&7
  const u16* gK = k + base + (size_t)r0 * DH + scg * 8;
  const u16* gV = vt + base + (size_t)r0 * SEQ + scg * 8;
  u16* sK0 = Ks + r0 * 64 + swzs;
  u16* sK1 = Ks + (r0 + 8) * 64 + swzs;
  u16* sV0 = Vs + r0 * 64 + swzs;
  u16* sV1 = Vs + (r0 + 8) * 64 + swzs;

  // Q fragments held in registers for the whole block
  frag_u qf[2][2];
  #pragma unroll
  for (int ni = 0; ni < 2; ni++)
    #pragma unroll
    for (int ks = 0; ks < 2; ks++)
      qf[ni][ks].u4 = *(const uint4*)(q + base +
          (size_t)(qBase + w * 32 + ni * 16 + l15) * DH + ks * 32 + quad * 8);

  f32x4 zero = {0.f, 0.f, 0.f, 0.f};
  f32x4 oacc[2][4];
  #pragma unroll
  for (int mi = 0; mi < 2; mi++)
    #pragma unroll
    for (int n0 = 0; n0 < 4; n0++) oacc[mi][n0] = zero;
  float l0 = 0.f, l1 = 0.f;

  uint4 rK0 = *(const uint4*)(gK);
  uint4 rK1 = *(const uint4*)(gK + 8 * DH);
  uint4 rV0 = *(const uint4*)(gV);
  uint4 rV1 = *(const uint4*)(gV + (size_t)8 * SEQ);

  for (int kt = 0; kt <= ktEnd; kt++) {
    __syncthreads();
    *(uint4*)sK0 = rK0; *(uint4*)sK1 = rK1;
    *(uint4*)sV0 = rV0; *(uint4*)sV1 = rV1;
    __syncthreads();
    if (kt < ktEnd) {
      const int no = (kt + 1) * 64;
      rK0 = *(const uint4*)(gK + (size_t)no * DH);
      rK1 = *(const uint4*)(gK + (size_t)(no + 8) * DH);
      rV0 = *(const uint4*)(gV + no);
      rV1 = *(const uint4*)(gV + (size_t)8 * SEQ + no);
    }
    const int rel = kt - 2 * qt;
    if (rel == 1 && w < 2) continue;   // fully-masked half-tile

    // K fragments (swizzled read, conflict-free)
    frag_u kf[4][2];
    #pragma unroll
    for (int mi = 0; mi < 4; mi++)
      #pragma unroll
      for (int ks = 0; ks < 2; ks++)
        kf[mi][ks].u4 = *(const uint4*)(Ks + (mi * 16 + l15) * 64 + (((ks * 4 + quad) ^ l7) * 8));
    f32x4 st[4][2];
    #pragma unroll
    for (int mi = 0; mi < 4; mi++)
      #pragma unroll
      for (int ni = 0; ni < 2; ni++) st[mi][ni] = zero;
    __builtin_amdgcn_s_setprio(1);
    #pragma unroll
    for (int ks = 0; ks < 2; ks++)
      #pragma unroll
      for (int mi = 0; mi < 4; mi++)
        #pragma unroll
        for (int ni = 0; ni < 2; ni++)
          st[mi][ni] = __builtin_amdgcn_mfma_f32_16x16x32_bf16(kf[mi][ks].bf, qf[ni][ks].bf, st[mi][ni], 0, 0, 0);
    __builtin_amdgcn_s_setprio(0);

    const bool doMask = (rel == 0 && w < 2) || (rel == 1);
    #pragma unroll
    for (int ni = 0; ni < 2; ni++) {
      const int qrow = qBase + w * 32 + ni * 16 + l15;
      float sum = 0.f;
      u16* prow = Ps + (w * 32 + ni * 16 + l15) * 64;   // row&7 == l7
      #pragma unroll
      for (int mi = 0; mi < 4; mi++) {
        float p[4];
        if (doMask) {
          #pragma unroll
          for (int r = 0; r < 4; r++) {
            p[r] = exp2_hw(st[mi][ni][r]);
            if ((kt * 64 + mi * 16 + quad * 4 + r) > qrow) p[r] = 0.f;
            sum += p[r];
          }
        } else {
          #pragma unroll
          for (int r = 0; r < 4; r++) {
            p[r] = exp2_hw(st[mi][ni][r]);
            sum += p[r];
          }
        }
        uint2 pk;
        pk.x = cvt_pk_bf16(p[0], p[1]);
        pk.y = cvt_pk_bf16(p[2], p[3]);
        // col = mi*16 + quad*4 -> group mi*2+(quad>>1), sub-offset (quad&1)*4
        *(uint2*)(prow + (((mi * 2 + (quad >> 1)) ^ l7) * 8) + (quad & 1) * 4) = pk;
      }
      sum += __shfl_xor(sum, 16, 64);
      sum += __shfl_xor(sum, 32, 64);
      if (ni == 0) l0 += sum; else l1 += sum;
    }

    frag_u pa[2][2];
    #pragma unroll
    for (int mi = 0; mi < 2; mi++)
      #pragma unroll
      for (int ks = 0; ks < 2; ks++)
        pa[mi][ks].u4 = *(const uint4*)(Ps + (w * 32 + mi * 16 + l15) * 64 + (((ks * 4 + quad) ^ l7) * 8));
    __builtin_amdgcn_s_setprio(1);
    #pragma unroll
    for (int ks = 0; ks < 2; ks++)
      #pragma unroll
      for (int n0 = 0; n0 < 4; n0++) {
        frag_u b;
        b.u4 = *(const uint4*)(Vs + (n0 * 16 + l15) * 64 + (((ks * 4 + quad) ^ l7) * 8));
        #pragma unroll
        for (int mi = 0; mi < 2; mi++)
          oacc[mi][n0] = __builtin_amdgcn_mfma_f32_16x16x32_bf16(pa[mi][ks].bf, b.bf, oacc[mi][n0], 0, 0, 0);
      }
    __builtin_amdgcn_s_setprio(0);
  }

  if (quad == 0) {
    Ls[w * 32 + l15] = l0;
    Ls[w * 32 + 16 + l15] = l1;
  }
  #pragma unroll
  for (int mi = 0; mi < 2; mi++) {
    float il[4];
    #pragma unroll
    for (int r = 0; r < 4; r++) il[r] = 1.f / Ls[w * 32 + mi * 16 + quad * 4 + r];
    #pragma unroll
    for (int n0 = 0; n0 < 4; n0++) {
      int s = qBase + w * 32 + mi * 16 + quad * 4;
      int col = hh * 64 + n0 * 16 + l15;
      #pragma unroll
      for (int r = 0; r < 4; r++)
        ctx[((size_t)(bq * SEQ + s + r)) * EMB + col] = f2bf(oacc[mi][n0][r] * il[r]);
    }
  }
}

extern "C" void kernel_launch(void* const* d_in, const int* in_sizes, int n_in,
                              void* d_out, int out_size, void* d_ws, size_t ws_size,
                              hipStream_t stream) {
  const float* x  = (const float*)d_in[0];
  const float* Wq = (const float*)d_in[1];
  const float* Wk = (const float*)d_in[2];
  const float* Wv = (const float*)d_in[3];
  const float* Wo = (const float*)d_in[4];
  const float* bo = (const float*)d_in[5];
  const float* W1 = (const float*)d_in[6];
  const float* b1 = (const float*)d_in[7];
  const float* W2 = (const float*)d_in[8];
  const float* b2 = (const float*)d_in[9];
  const float* g1  = (const float*)d_in[10];
  const float* be1 = (const float*)d_in[11];
  const float* g2  = (const float*)d_in[12];
  const float* be2 = (const float*)d_in[13];
  float* out = (float*)d_out;
  char* ws = (char*)d_ws;
  const size_t MB = 1u << 20;

  u16* wqkv_t = (u16*)(ws + 0 * MB);          // 6 MB
  u16* wo_t   = (u16*)(ws + 6 * MB);          // 2 MB
  u16* w1_t   = (u16*)(ws + 8 * MB);          // 8 MB
  u16* w2_t   = (u16*)(ws + 16 * MB);         // 8 MB
  u16* hbuf   = (u16*)(ws + 24 * MB);         // 16 MB bf16 residual h
  u16* r1 = (u16*)(ws + 56 * MB);             // 16 MB: xn1 -> ctx -> xn2
  u16* qb = (u16*)(ws + 72 * MB);             // q,k 16 MB each; vt 16 MB [bh][d][s]
  u16* f1 = (u16*)(ws + 72 * MB);             // 64 MB, overlaps q/k/vt (dead after attn)

  // 1. all weights -> bf16 transposed + LN1(x) -> xn1 (single dispatch; R7 bodies)
  prep_kernel<<<14336, 256, 0, stream>>>(Wq, Wk, Wv, Wo, W1, W2,
                                         wqkv_t, wo_t, w1_t, w2_t,
                                         x, g1, be1, r1);

  // 2. fused QKV (256x128 tiles); q,k row-major, v transposed to [bh][d][s]
  gemm256<1><<<dim3(24, 32), 512, 0, stream>>>(r1, wqkv_t, nullptr, qb, 3072, 1024);

  // 3. causal attention -> ctx  (one q-tile per block, heavy-first)
  attn_kernel<<<dim3(64, 16), 256, 0, stream>>>(qb, qb + (size_t)TOK * EMB,
                                                qb + 2 * (size_t)TOK * EMB, r1);

  // 4. Wo + bo + x -> h (bf16)
  gemm128<3><<<dim3(8, 64), 256, 0, stream>>>(r1, wo_t, bo, x, hbuf, 1024, 1024);

  // 5. LN2(h) -> xn2
  ln_kernel<1><<<2048, 256, 0, stream>>>(hbuf, g2, be2, r1);

  // 6. FFN1: GELU(xn2 @ W1 + b1) -> f1 (256x128 tiles)
  gemm256<2><<<dim3(32, 32), 512, 0, stream>>>(r1, w1_t, b1, f1, 4096, 1024);

  // 7. FFN2: f1 @ W2 + b2 + h -> out (fp32)
  gemm128<4><<<dim3(8, 64), 256, 0, stream>>>(f1, w2_t, b2, hbuf, out, 1024, 4096);
}